// Round 2
// baseline (382.008 us; speedup 1.0000x reference)
//
#include <hip/hip_runtime.h>
#include <hip/hip_bf16.h>
#include <hip/hip_fp16.h>

// ---------------------------------------------------------------------------
// GNN: h = relu(GCN(x)); h = relu(GAT(h)); h = relu(GCN(h)); h = relu(GAT(h));
//      z = h @ Wo + bo.  Outputs: [h (N*128), z (N*64)] fp32.
// R10: aggregation restructured for XCD-L2 locality. The 12.8MB fp16 feature
//     buffer never fit one XCD's 4MB L2 -> 47us latency-bound gathers (85MB
//     TCC miss traffic each). Now: GEMM writes xw SLICE-MAJOR [4][Nn][32]
//     (3.2MB per slice < 4MB L2); k_agg partitions work so slice =
//     blockIdx&3 and blocks round-robin XCDs -> each XCD gathers only from
//     its own L2-resident slice. Per-edge weights hoisted: k_wgcn packs
//     (src, inv*inv) once (both GCN layers), k_alpha packs (src, alpha) per
//     GAT layer (same softmax math as R6-R9 fused path). k_agg = pure
//     weighted gather, 4 lanes/node, serial per-lane accum, no shfl.
//     Build (R7 bucket sort) and GEMM (R9 frag-major, 64 rows/blk) unchanged.
// ---------------------------------------------------------------------------

#define WAVE 64
#define BK 256        // nodes per bucket
#define CHUNK 4096    // edges per k_bscatter block
#define NSLICE 4      // feature slices (32 features = 64B fp16 each)

typedef _Float16 f16x8 __attribute__((ext_vector_type(8)));
typedef float f32x4 __attribute__((ext_vector_type(4)));

__global__ void k_zero_i32(int* __restrict__ p, int n) {
    int i = blockIdx.x * 256 + threadIdx.x;
    if (i < n) p[i] = 0;
}

// ------------------------------ graph build --------------------------------
// edge e in [0,E): (s,d) = (ei[e], ei[E+e]); e in [E,Et): self-loop (e-E,e-E)

__global__ __launch_bounds__(256) void k_bhist(
    const int* __restrict__ ei, int* __restrict__ bcnt,
    int E, int Et, int nbuck) {
    __shared__ int hist[256];
    int tid = threadIdx.x;
    if (tid < nbuck) hist[tid] = 0;
    __syncthreads();
    for (int e = blockIdx.x * 256 + tid; e < Et; e += gridDim.x * 256) {
        int d = (e < E) ? ei[E + e] : (e - E);
        atomicAdd(&hist[d >> 8], 1);
    }
    __syncthreads();
    if (tid < nbuck && hist[tid] > 0) atomicAdd(&bcnt[tid], hist[tid]);
}

__global__ void k_bscan(const int* __restrict__ bcnt, int* __restrict__ bbase,
                        int* __restrict__ bcur, int nbuck) {
    __shared__ int tmp[256];
    int tid = threadIdx.x;
    int v = (tid < nbuck) ? bcnt[tid] : 0;
    tmp[tid] = v;
    __syncthreads();
    for (int off = 1; off < 256; off <<= 1) {
        int t = (tid >= off) ? tmp[tid - off] : 0;
        __syncthreads();
        tmp[tid] += t;
        __syncthreads();
    }
    if (tid < nbuck) {
        int excl = tmp[tid] - v;
        bbase[tid] = excl;
        bcur[tid] = excl;
        if (tid == nbuck - 1) bbase[nbuck] = tmp[tid];
    }
}

__global__ __launch_bounds__(256) void k_bscatter(
    const int* __restrict__ ei, int* __restrict__ bcur,
    int2* __restrict__ ebuf, int E, int Et, int nbuck) {
    __shared__ int hist[256];
    __shared__ int base[256];
    __shared__ int off[256];
    constexpr int PT = CHUNK / 256;   // 16 edges per thread
    int tid = threadIdx.x;
    int cb = blockIdx.x * CHUNK;
    if (tid < nbuck) { hist[tid] = 0; off[tid] = 0; }
    __syncthreads();

    int sv[PT], dv[PT];
#pragma unroll
    for (int i = 0; i < PT; ++i) {
        int e = cb + i * 256 + tid;
        int s = 0, d = -1;
        if (e < Et) {
            if (e < E) { s = ei[e]; d = ei[E + e]; }
            else       { s = d = e - E; }
            atomicAdd(&hist[d >> 8], 1);
        }
        sv[i] = s; dv[i] = d;
    }
    __syncthreads();
    if (tid < nbuck && hist[tid] > 0)
        base[tid] = atomicAdd(&bcur[tid], hist[tid]);
    __syncthreads();
#pragma unroll
    for (int i = 0; i < PT; ++i) {
        if (dv[i] >= 0) {
            int b = dv[i] >> 8;
            int pos = base[b] + atomicAdd(&off[b], 1);
            ebuf[pos] = make_int2(sv[i], dv[i]);
        }
    }
}

__global__ __launch_bounds__(256) void k_csr(
    const int2* __restrict__ ebuf, const int* __restrict__ bbase,
    int* __restrict__ rowp, float* __restrict__ inv, int* __restrict__ esrc,
    int Nn, int Et) {
    __shared__ int hist[256];
    __shared__ int scan[256];
    __shared__ int cur[256];
    int tid = threadIdx.x;
    int b = blockIdx.x;
    int bb = bbase[b], cnt = bbase[b + 1] - bb;
    hist[tid] = 0;
    __syncthreads();
    for (int t = tid; t < cnt; t += 256)
        atomicAdd(&hist[ebuf[bb + t].y & 255], 1);
    __syncthreads();
    int v = hist[tid];
    scan[tid] = v;
    __syncthreads();
    for (int o = 1; o < 256; o <<= 1) {
        int t = (tid >= o) ? scan[tid - o] : 0;
        __syncthreads();
        scan[tid] += t;
        __syncthreads();
    }
    int excl = scan[tid] - v;
    int node = b * BK + tid;
    if (node < Nn) {
        rowp[node] = bb + excl;
        inv[node] = rsqrtf((float)v);
    }
    cur[tid] = excl;
    if (b == 0 && tid == 0) rowp[Nn] = Et;
    __syncthreads();
    for (int t = tid; t < cnt; t += 256) {
        int2 e = ebuf[bb + t];
        int pos = bb + atomicAdd(&cur[e.y & 255], 1);
        esrc[pos] = e.x;
    }
}

// -------------------- weight convert (fp32 -> fp16, fragment-major) --------
// Wt layout: [0]W1 [16384]Wg1 [32768]W2 [49152]Wg2 [65536]Wo
// Within each weight, B-fragments stored contiguously:
//   elem ((nt*4 + ks)*64 + lane)*8 + j  =  W[k][n]
//   with n = nt*16 + (lane&15), k = ks*32 + (lane>>4)*8 + j.

__global__ void k_wcvt(const float* __restrict__ W1, const float* __restrict__ Wg1,
                       const float* __restrict__ W2, const float* __restrict__ Wg2,
                       const float* __restrict__ Wo, __half* __restrict__ Wt) {
    int i = blockIdx.x * 256 + threadIdx.x;   // 73728 total
    if (i < 65536) {
        int w = i >> 14;
        int j = i & 16383;
        int nt = j >> 11, ks = (j >> 9) & 3, lane = (j >> 3) & 63, jj = j & 7;
        int n = nt * 16 + (lane & 15);
        int k = ks * 32 + (lane >> 4) * 8 + jj;
        const float* W = (w == 0) ? W1 : (w == 1) ? Wg1 : (w == 2) ? W2 : Wg2;
        Wt[i] = __float2half(W[k * 128 + n]);
    } else if (i < 73728) {
        int j = i - 65536;                    // 8192: Wo is 128x64 -> NT=4
        int nt = j >> 11, ks = (j >> 9) & 3, lane = (j >> 3) & 63, jj = j & 7;
        int n = nt * 16 + (lane & 15);
        int k = ks * 32 + (lane >> 4) * 8 + jj;
        Wt[65536 + j] = __float2half(Wo[k * 64 + n]);
    }
}

// ------------------------------ MFMA GEMM ----------------------------------
// out[M x NC] = A(fp32 M x 128) @ W(fp16, fragment-major Wt) ; fp32 accum.
// 256 thr = 4 waves, one 16-row m-tile per wave -> 64 rows/block.
// fp16 output (NC=128) is written SLICE-MAJOR: [4][M][32] halfs, slice=col>>5,
// so the agg's per-XCD gather working set is one contiguous 3.2MB region.
// fp32 output (NC=64, final layer) stays node-major with bias.
// If asrc!=null, GAT alpha logits reduced from fp32 accumulators.

template <int NC, typename OT>
__global__ __launch_bounds__(256) void gemm_mfma(
    const float* __restrict__ A, const __half* __restrict__ Wt,
    const float* __restrict__ bias, OT* __restrict__ out,
    const float* __restrict__ asrc, const float* __restrict__ adst,
    float* __restrict__ alS, float* __restrict__ alD, int M) {
    constexpr int NT = NC / 16;
    __shared__ f16x8 Wl[NC * 16];             // NC*128 halfs, fragment-major
    const int tid = threadIdx.x;
    const int wv = tid >> 6, lane = tid & 63;
    const int m16 = lane & 15, quad = lane >> 4;

#pragma unroll
    for (int i = tid; i < NC * 16; i += 256)
        Wl[i] = ((const f16x8*)Wt)[i];
    __syncthreads();

    const int row0 = blockIdx.x * 64 + wv * 16;

    f16x8 af[4];
    {
        int row = row0 + m16;
        if (row > M - 1) row = M - 1;
        const float* ap = A + (size_t)row * 128 + quad * 8;
#pragma unroll
        for (int ks = 0; ks < 4; ++ks) {
            float4 lo = *(const float4*)(ap + ks * 32);
            float4 hi = *(const float4*)(ap + ks * 32 + 4);
            f16x8 v;
            v[0] = (_Float16)lo.x; v[1] = (_Float16)lo.y;
            v[2] = (_Float16)lo.z; v[3] = (_Float16)lo.w;
            v[4] = (_Float16)hi.x; v[5] = (_Float16)hi.y;
            v[6] = (_Float16)hi.z; v[7] = (_Float16)hi.w;
            af[ks] = v;
        }
    }

    f32x4 acc[NT];
#pragma unroll
    for (int nt = 0; nt < NT; ++nt)
        acc[nt] = (f32x4){0.f, 0.f, 0.f, 0.f};

#pragma unroll
    for (int ks = 0; ks < 4; ++ks) {
#pragma unroll
        for (int nt = 0; nt < NT; ++nt) {
            f16x8 bf = Wl[(nt * 4 + ks) * 64 + lane];
            acc[nt] = __builtin_amdgcn_mfma_f32_16x16x32_f16(
                af[ks], bf, acc[nt], 0, 0, 0);
        }
    }

    // fused GAT alpha: s = xw.asrc, d = xw.adst per row (from fp32 accum)
    if (asrc) {
        float sa[NT], da[NT];
#pragma unroll
        for (int nt = 0; nt < NT; ++nt) {
            sa[nt] = asrc[nt * 16 + m16];
            da[nt] = adst[nt * 16 + m16];
        }
#pragma unroll
        for (int r = 0; r < 4; ++r) {
            float s = 0.f, d = 0.f;
#pragma unroll
            for (int nt = 0; nt < NT; ++nt) {
                s = fmaf(acc[nt][r], sa[nt], s);
                d = fmaf(acc[nt][r], da[nt], d);
            }
#pragma unroll
            for (int off = 8; off > 0; off >>= 1) {
                s += __shfl_xor(s, off);
                d += __shfl_xor(d, off);
            }
            int row = row0 + quad * 4 + r;
            if (m16 == 0 && row < M) { alS[row] = s; alD[row] = d; }
        }
    }

#pragma unroll
    for (int nt = 0; nt < NT; ++nt) {
#pragma unroll
        for (int r = 0; r < 4; ++r) {
            int row = row0 + quad * 4 + r;
            if (row < M) {
                float v = acc[nt][r];
                int col = nt * 16 + m16;
                if constexpr (sizeof(OT) == 2) {
                    // slice-major: [slice][M][32] halfs, slice = col>>5
                    size_t addr = ((size_t)(col >> 5) * M + row) * 32 + (col & 31);
                    ((__half*)out)[addr] = __float2half(v);
                } else {
                    ((float*)out)[(size_t)row * NC + col] = v + bias[col];
                }
            }
        }
    }
}

// ------------------------- per-edge weight kernels -------------------------
// Hoisted out of the agg so the sliced agg (x4 passes) doesn't redo them.
// ew[e] = (src_id, weight-as-int-bits). One wave per node, wave-uniform exit.

__global__ __launch_bounds__(256) void k_wgcn(
    const int* __restrict__ rowp, const int* __restrict__ esrc,
    const float* __restrict__ inv, int2* __restrict__ ew, int Nn) {
    int gid = blockIdx.x * 256 + threadIdx.x;
    int n = gid >> 6, lane = gid & 63;
    if (n >= Nn) return;
    int beg = rowp[n], end = rowp[n + 1];
    float invd = inv[n];
    for (int e = beg + lane; e < end; e += WAVE) {
        int sid = esrc[e];
        ew[e] = make_int2(sid, __float_as_int(invd * inv[sid]));
    }
}

__global__ __launch_bounds__(256) void k_alpha(
    const int* __restrict__ rowp, const int* __restrict__ esrc,
    const float* __restrict__ as_, const float* __restrict__ ad_,
    int2* __restrict__ ew, int Nn) {
    int gid = blockIdx.x * 256 + threadIdx.x;
    int n = gid >> 6, lane = gid & 63;
    if (n >= Nn) return;
    int beg = rowp[n], end = rowp[n + 1];
    int deg = end - beg;
    float adn = ad_[n];

    if (deg <= WAVE) {
        // fast path (deg<=64, ~all nodes) — same math as R6-R9 fused path
        bool valid = (lane < deg);
        int sid = 0;
        float v = -1e30f;
        if (valid) {
            sid = esrc[beg + lane];
            float t = as_[sid] + adn;
            v = (t > 0.f) ? t : 0.2f * t;
        }
        float m = v;
#pragma unroll
        for (int off = 32; off > 0; off >>= 1) m = fmaxf(m, __shfl_xor(m, off));
        float ex = valid ? __expf(v - m) : 0.f;
        float ssum = ex;
#pragma unroll
        for (int off = 32; off > 0; off >>= 1) ssum += __shfl_xor(ssum, off);
        float wgt = ex * (1.f / ssum);
        if (valid) ew[beg + lane] = make_int2(sid, __float_as_int(wgt));
    } else {
        // generic two-pass path (deg>64: essentially never at E/N=16)
        float m = -1e30f, ssum = 0.f;
        for (int e = beg + lane; e < end; e += WAVE) {
            float v = as_[esrc[e]] + adn;
            v = (v > 0.f) ? v : 0.2f * v;
            float mn = fmaxf(m, v);
            ssum = ssum * __expf(m - mn) + __expf(v - mn);
            m = mn;
        }
#pragma unroll
        for (int off = 32; off > 0; off >>= 1) {
            float mo = __shfl_xor(m, off);
            float so = __shfl_xor(ssum, off);
            float mn = fmaxf(m, mo);
            ssum = ssum * __expf(m - mn) + so * __expf(mo - mn);
            m = mn;
        }
        float rden = 1.f / ssum;
        for (int e = beg + lane; e < end; e += WAVE) {
            int sid = esrc[e];
            float v = as_[sid] + adn;
            v = (v > 0.f) ? v : 0.2f * v;
            ew[e] = make_int2(sid, __float_as_int(__expf(v - m) * rden));
        }
    }
}

// ------------------------- sliced weighted aggregation ---------------------
// xw2: [NSLICE][Nn][32] halfs (slice-major, 3.2MB per slice -> fits XCD L2).
// slice = blockIdx&3; blocks round-robin XCDs so XCD x touches only slice x%4.
// 4 lanes per node (q = lane&3 owns features q*8..q*8+8 of the slice); each
// lane serially accumulates over the node's edge list: no cross-lane reduce.
// ew = packed (src, weight). Output fp32 node-major with bias+relu.

__device__ __forceinline__ void acc8(float acc[8], float4 v, float w) {
    const __half2* h2 = (const __half2*)&v;
#pragma unroll
    for (int i = 0; i < 4; ++i) {
        float2 f = __half22float2(h2[i]);
        acc[2 * i]     = fmaf(w, f.x, acc[2 * i]);
        acc[2 * i + 1] = fmaf(w, f.y, acc[2 * i + 1]);
    }
}

__global__ __launch_bounds__(256) void k_agg(
    const __half* __restrict__ xw2, const int* __restrict__ rowp,
    const int2* __restrict__ ew, const float* __restrict__ bias,
    float* __restrict__ out, int Nn) {
    int tid = threadIdx.x;
    int slice = blockIdx.x & 3;
    int nb = blockIdx.x >> 2;
    int wv = tid >> 6, lane = tid & 63;
    int n = nb * 64 + wv * 16 + (lane >> 2);
    int q = lane & 3;
    if (n >= Nn) return;
    int beg = rowp[n], end = rowp[n + 1];
    const __half* xs = xw2 + (size_t)slice * Nn * 32 + q * 8;

    float acc[8] = {0.f, 0.f, 0.f, 0.f, 0.f, 0.f, 0.f, 0.f};
    int e = beg;
    for (; e + 4 <= end; e += 4) {
        int2 p0 = ew[e], p1 = ew[e + 1], p2 = ew[e + 2], p3 = ew[e + 3];
        float4 v0 = *(const float4*)(xs + (size_t)p0.x * 32);
        float4 v1 = *(const float4*)(xs + (size_t)p1.x * 32);
        float4 v2 = *(const float4*)(xs + (size_t)p2.x * 32);
        float4 v3 = *(const float4*)(xs + (size_t)p3.x * 32);
        acc8(acc, v0, __int_as_float(p0.y));
        acc8(acc, v1, __int_as_float(p1.y));
        acc8(acc, v2, __int_as_float(p2.y));
        acc8(acc, v3, __int_as_float(p3.y));
    }
    for (; e < end; ++e) {
        int2 p = ew[e];
        float4 v = *(const float4*)(xs + (size_t)p.x * 32);
        acc8(acc, v, __int_as_float(p.y));
    }

    const float* bp = bias + slice * 32 + q * 8;
    float4 b0 = *(const float4*)(bp);
    float4 b1 = *(const float4*)(bp + 4);
    float4 r0, r1;
    r0.x = fmaxf(acc[0] + b0.x, 0.f);
    r0.y = fmaxf(acc[1] + b0.y, 0.f);
    r0.z = fmaxf(acc[2] + b0.z, 0.f);
    r0.w = fmaxf(acc[3] + b0.w, 0.f);
    r1.x = fmaxf(acc[4] + b1.x, 0.f);
    r1.y = fmaxf(acc[5] + b1.y, 0.f);
    r1.z = fmaxf(acc[6] + b1.z, 0.f);
    r1.w = fmaxf(acc[7] + b1.w, 0.f);
    float4* o = (float4*)(out + (size_t)n * 128 + slice * 32 + q * 8);
    o[0] = r0;
    o[1] = r1;
}

// ------------------------------- launch ------------------------------------

extern "C" void kernel_launch(void* const* d_in, const int* in_sizes, int n_in,
                              void* d_out, int out_size, void* d_ws, size_t ws_size,
                              hipStream_t stream) {
    const float* x   = (const float*)d_in[0];
    const int*   ei  = (const int*)d_in[1];
    const float* W1  = (const float*)d_in[2];
    const float* b1  = (const float*)d_in[3];
    const float* Wg1 = (const float*)d_in[4];
    const float* as1 = (const float*)d_in[5];
    const float* ad1 = (const float*)d_in[6];
    const float* bg1 = (const float*)d_in[7];
    const float* W2  = (const float*)d_in[8];
    const float* b2  = (const float*)d_in[9];
    const float* Wg2 = (const float*)d_in[10];
    const float* as2 = (const float*)d_in[11];
    const float* ad2 = (const float*)d_in[12];
    const float* bg2 = (const float*)d_in[13];
    const float* Wo  = (const float*)d_in[14];
    const float* bo  = (const float*)d_in[15];

    const int Nn = in_sizes[0] / 128;
    const int E  = in_sizes[1] / 2;
    const int Et = E + Nn;
    const int H  = 128;
    const int nbuck = (Nn + BK - 1) / BK;   // 196

    float* outH = (float*)d_out;
    float* outZ = outH + (size_t)Nn * H;

    char* p = (char*)d_ws;
    auto carve = [&](size_t bytes) {
        char* r = p;
        p += (bytes + 255) & ~(size_t)255;
        return r;
    };
    __half* bufA = (__half*)carve((size_t)Nn * H * sizeof(__half));  // xw [4][Nn][32]
    __half* Wt   = (__half*)carve((size_t)73728 * sizeof(__half));   // fp16 W frags x5
    float* alS   = (float*)carve((size_t)Nn * sizeof(float));
    float* alD   = (float*)carve((size_t)Nn * sizeof(float));
    float* inv   = (float*)carve((size_t)Nn * sizeof(float));
    int*   rowp  = (int*)carve((size_t)(Nn + 1) * sizeof(int));
    int*   esrc  = (int*)carve((size_t)Et * sizeof(int));
    int2*  ebuf  = (int2*)carve((size_t)Et * sizeof(int2));
    int2*  ewg   = (int2*)carve((size_t)Et * sizeof(int2));          // GCN (src,w)
    int*   bcnt  = (int*)carve((size_t)nbuck * sizeof(int));
    int*   bbase = (int*)carve((size_t)(nbuck + 1) * sizeof(int));
    int*   bcur  = (int*)carve((size_t)nbuck * sizeof(int));
    (void)ws_size; (void)n_in; (void)out_size;

    // ebuf is dead after k_csr; reuse it as the GAT (src,alpha) buffer
    int2* ewa = ebuf;

    const int nodeWaves = (Nn * WAVE + 255) / 256;   // 12500: wave-per-node grids
    const int gemmB = (Nn + 63) / 64;                // 782
    const int aggB  = ((Nn + 63) / 64) * NSLICE;     // 3128: 64 nodes x 4 slices
    const int scatB = (Et + CHUNK - 1) / CHUNK;      // 208

    // graph build (two-level bucket sort)
    k_zero_i32<<<1, 256, 0, stream>>>(bcnt, nbuck);
    k_bhist<<<104, 256, 0, stream>>>(ei, bcnt, E, Et, nbuck);
    k_bscan<<<1, 256, 0, stream>>>(bcnt, bbase, bcur, nbuck);
    k_bscatter<<<scatB, 256, 0, stream>>>(ei, bcur, ebuf, E, Et, nbuck);
    k_csr<<<nbuck, 256, 0, stream>>>(ebuf, bbase, rowp, inv, esrc, Nn, Et);
    k_wcvt<<<288, 256, 0, stream>>>(W1, Wg1, W2, Wg2, Wo, Wt);
    k_wgcn<<<nodeWaves, 256, 0, stream>>>(rowp, esrc, inv, ewg, Nn);

    gemm_mfma<128, __half><<<gemmB, 256, 0, stream>>>(
        x, Wt, nullptr, bufA, nullptr, nullptr, nullptr, nullptr, Nn);
    k_agg<<<aggB, 256, 0, stream>>>(bufA, rowp, ewg, b1, outH, Nn);

    gemm_mfma<128, __half><<<gemmB, 256, 0, stream>>>(
        outH, Wt + 16384, nullptr, bufA, as1, ad1, alS, alD, Nn);
    k_alpha<<<nodeWaves, 256, 0, stream>>>(rowp, esrc, alS, alD, ewa, Nn);
    k_agg<<<aggB, 256, 0, stream>>>(bufA, rowp, ewa, bg1, outH, Nn);

    gemm_mfma<128, __half><<<gemmB, 256, 0, stream>>>(
        outH, Wt + 32768, nullptr, bufA, nullptr, nullptr, nullptr, nullptr, Nn);
    k_agg<<<aggB, 256, 0, stream>>>(bufA, rowp, ewg, b2, outH, Nn);

    gemm_mfma<128, __half><<<gemmB, 256, 0, stream>>>(
        outH, Wt + 49152, nullptr, bufA, as2, ad2, alS, alD, Nn);
    k_alpha<<<nodeWaves, 256, 0, stream>>>(rowp, esrc, alS, alD, ewa, Nn);
    k_agg<<<aggB, 256, 0, stream>>>(bufA, rowp, ewa, bg2, outH, Nn);

    gemm_mfma<64, float><<<gemmB, 256, 0, stream>>>(
        outH, Wt + 65536, bo, outZ, nullptr, nullptr, nullptr, nullptr, Nn);
}